// Round 13
// baseline (196.456 us; speedup 1.0000x reference)
//
#include <hip/hip_runtime.h>

#define IN_F 512
#define OUT_F 1024
#define K_ACTIVE 11  // ceil(0.01 * 1024) serial MP steps
#define K_IN 6       // ceil(0.01 * 512) kwta winners

// ---- w [1024][512] f32 -> wT [513][1024] f32 (row 512 = zeros, odd-cnt pad) ----
// wT is 2.1 MB: fits per-XCD L2 (4 MiB) together with w (2 MB). R6 measured fp64
// wT (4.2 MB) thrashing L2 -> 156 MB HBM fetch, +34 us. Keep f32.
__global__ __launch_bounds__(256) void transpose_w_kernel(const float* __restrict__ w,
                                                          float* __restrict__ wT) {
    __shared__ float tile[32][33];
    const int tx = threadIdx.x & 31;
    const int ty = threadIdx.x >> 5;  // 0..7
    const int i0 = blockIdx.x * 32;
    const int j0 = blockIdx.y * 32;
#pragma unroll
    for (int k = 0; k < 4; ++k)
        tile[ty + 8 * k][tx] = w[(size_t)(j0 + ty + 8 * k) * IN_F + (i0 + tx)];
    __syncthreads();
#pragma unroll
    for (int k = 0; k < 4; ++k)
        wT[(size_t)(i0 + ty + 8 * k) * OUT_F + (j0 + tx)] = tile[tx][ty + 8 * k];
}
__global__ void zero_row_f_kernel(float* __restrict__ wT) {
    wT[(size_t)IN_F * OUT_F + blockIdx.x * 256 + threadIdx.x] = 0.0f;
}

// ---- order-preserving fp64 -> u64 key, low bits carry reversed index ----
__device__ __forceinline__ unsigned long long pack_key(double v, unsigned rev,
                                                       unsigned long long mask) {
    unsigned long long b = (unsigned long long)__double_as_longlong(v);
    unsigned long long m =
        (unsigned long long)((long long)b >> 63) | 0x8000000000000000ull;
    unsigned long long u = b ^ m;  // monotonic total order
    return (u & ~mask) | (unsigned long long)rev;
}

// ---- monotonic u32 key from the f64 HIGH word ----
__device__ __forceinline__ unsigned hi_key(double v) {
    const int hi = __double2hiint(v);
    return (unsigned)hi ^ ((unsigned)(hi >> 31) | 0x80000000u);
}

// ---- wave max of u32 via DPP chain (bound_ctrl=true: invalid lanes -> 0) ----
template <int C>
__device__ __forceinline__ unsigned maxdpp(unsigned v) {
    unsigned t = (unsigned)__builtin_amdgcn_update_dpp(0, (int)v, C, 0xF, 0xF, true);
    return t > v ? t : v;
}
__device__ __forceinline__ unsigned wave_umax(unsigned v) {
    v = maxdpp<0x111>(v);  // row_shr:1
    v = maxdpp<0x112>(v);  // row_shr:2
    v = maxdpp<0x114>(v);  // row_shr:4
    v = maxdpp<0x118>(v);  // row_shr:8
    v = maxdpp<0x142>(v);  // row_bcast:15
    v = maxdpp<0x143>(v);  // row_bcast:31 -> lane 63 holds wave max
    return (unsigned)__builtin_amdgcn_readlane((int)v, 63);
}

// ---- exact wave max of u64 key (rare path): high32 chain + tie resolve ----
__device__ __forceinline__ unsigned long long wave_max_key(unsigned long long k) {
    const unsigned h = (unsigned)(k >> 32), l = (unsigned)k;
    const unsigned gh = wave_umax(h);
    const unsigned long long tied = __ballot(h == gh);
    unsigned gl;
    if (__popcll(tied) == 1) {
        gl = (unsigned)__builtin_amdgcn_readlane((int)l,
                                                 (int)__ffsll((long long)tied) - 1);
    } else {
        gl = wave_umax((h == gh) ? l : 0u);
    }
    return ((unsigned long long)gh << 32) | gl;
}

// half-row paired add (projection): rh[s] over j = wv*512 + (s>>2)*256 + lane*4 + (s&3)
__device__ __forceinline__ void half_add2(double* rh, const float* __restrict__ wT,
                                          int i0, int i1, int lane, int wv) {
    const float* p0 = wT + ((size_t)i0 << 10) + (wv << 9) + (lane << 2);
    const float* p1 = wT + ((size_t)i1 << 10) + (wv << 9) + (lane << 2);
    const float4 f0 = *(const float4*)(p0);
    const float4 f1 = *(const float4*)(p0 + 256);
    const float4 g0 = *(const float4*)(p1);
    const float4 g1 = *(const float4*)(p1 + 256);
    rh[0] += (double)f0.x + (double)g0.x;  rh[1] += (double)f0.y + (double)g0.y;
    rh[2] += (double)f0.z + (double)g0.z;  rh[3] += (double)f0.w + (double)g0.w;
    rh[4] += (double)f1.x + (double)g1.x;  rh[5] += (double)f1.y + (double)g1.y;
    rh[6] += (double)f1.z + (double)g1.z;  rh[7] += (double)f1.w + (double)g1.w;
}

// half-row axpy (residual update): same slot layout, 2 coalesced float4 loads
__device__ __forceinline__ void half_axpy(double* rh, const float* __restrict__ wT,
                                          int i, double sgn, int lane, int wv) {
    const float* rp = wT + ((size_t)i << 10) + (wv << 9) + (lane << 2);
    const float4 f0 = *(const float4*)(rp);
    const float4 f1 = *(const float4*)(rp + 256);
    rh[0] += sgn * (double)f0.x;  rh[1] += sgn * (double)f0.y;
    rh[2] += sgn * (double)f0.z;  rh[3] += sgn * (double)f0.w;
    rh[4] += sgn * (double)f1.x;  rh[5] += sgn * (double)f1.y;
    rh[6] += sgn * (double)f1.z;  rh[7] += sgn * (double)f1.w;
}

// MODE0 fallbacks (no workspace): strided gathers from row-major w
__device__ __forceinline__ void half_add0(double* rh, const float* __restrict__ w,
                                          int i, int lane, int wv) {
#pragma unroll
    for (int s = 0; s < 8; ++s) {
        const int j = (wv << 9) | ((s >> 2) << 8) | (lane << 2) | (s & 3);
        rh[s] += (double)w[(size_t)j * IN_F + i];
    }
}
__device__ __forceinline__ void half_axpy0(double* rh, const float* __restrict__ w,
                                           int i, double sgn, int lane, int wv) {
#pragma unroll
    for (int s = 0; s < 8; ++s) {
        const int j = (wv << 9) | ((s >> 2) << 8) | (lane << 2) | (s & 3);
        rh[s] += sgn * (double)w[(size_t)j * IN_F + i];
    }
}

// TWO ROWS per 2-wave block, ROLE-SWAPPED (R13): each wave owns the OUT-half of
// BOTH rows' residuals (rA[8], rB[8]) and the FULL v+kwta of ONE row (wave0=A,
// wave1=B). Per step: 2 half-argmaxes per wave (independent chains = intra-wave
// ILP) -> B1 -> merge both rows -> each wave runs one full kwta (no duplication
// [R12's waste], no parking [R10's 44% busy cap]) -> B2 -> set-diff axpys on
// both rows. __launch_bounds__(128,4): 4 waves/EU -> 128-VGPR budget for the
// ~75-VGPR peak (grid is exactly 4 waves/SIMD, so nothing is sacrificed).
template <int MODE>
__global__ __launch_bounds__(128, 4) void bmp_kernel(const float* __restrict__ x,
                                                     const float* __restrict__ w,
                                                     const float* __restrict__ wT,
                                                     float* __restrict__ out,
                                                     int rows) {
    __shared__ unsigned short act[2][IN_F + 8];
    __shared__ int cntS[2];
    __shared__ unsigned gu32[2][2];       // [row][wv] argmax merge (u32 key)
    __shared__ int gjw[2][2];             // [row][wv] argmax merge (index)
    __shared__ unsigned long long kx[2][2];  // rare exact cross-wave u64 merge
    __shared__ int msg[2][8];             // [row][1..6] kwta winners
    const int lane = threadIdx.x & 63;
    const int wv = threadIdx.x >> 6;
    const int rowA = blockIdx.x * 2;
    if (rowA >= rows) return;
    int rowB = rowA + 1;
    if (rowB >= rows) rowB = rowA;  // clamp (rows=4096 even: never taken)
    const int myrow = wv ? rowB : rowA;

    // ---- each wave builds the active list of ITS row (ballots are wave-local) ----
    {
        const float* xrow = x + (size_t)myrow * IN_F;
        int cnt = 0;
#pragma unroll
        for (int c = 0; c < IN_F / 64; ++c) {
            bool pbit = xrow[c * 64 + lane] != 0.0f;
            unsigned long long m = __ballot(pbit);
            int pre = __popcll(m & ((1ull << lane) - 1ull));
            if (pbit) act[wv][cnt + pre] = (unsigned short)(c * 64 + lane);
            cnt += __popcll(m);
        }
        if (lane < 2) act[wv][cnt + lane] = (unsigned short)IN_F;  // zero-row pad
        if (lane == 0) cntS[wv] = cnt;
    }
    __syncthreads();
    const int cntA = cntS[0], cntB = cntS[1];

    // ---- projection: own OUT-half of BOTH rows (fp64, incremental later) ----
    double rA[8], rB[8];
#pragma unroll
    for (int s = 0; s < 8; ++s) { rA[s] = 0.0; rB[s] = 0.0; }
    if constexpr (MODE == 1) {
#pragma unroll 1
        for (int k = 0; k < cntA; k += 2)
            half_add2(rA, wT, act[0][k], act[0][k + 1], lane, wv);
#pragma unroll 1
        for (int k = 0; k < cntB; k += 2)
            half_add2(rB, wT, act[1][k], act[1][k + 1], lane, wv);
    } else {
#pragma unroll 1
        for (int k = 0; k < cntA; ++k) half_add0(rA, w, act[0][k], lane, wv);
#pragma unroll 1
        for (int k = 0; k < cntB; ++k) half_add0(rB, w, act[1][k], lane, wv);
    }
#pragma unroll
    for (int s = 0; s < 8; ++s) { rA[s] *= 2.0; rB[s] *= 2.0; }

    double vd[8];  // FULL v of OWN row (wave0: rowA, wave1: rowB)
#pragma unroll
    for (int p = 0; p < 8; ++p) vd[p] = 0.0;

    unsigned encA = 0, encB = 0;  // per-lane 8-bit masks over own OUT-half slots
    unsigned selmask = 0;         // own row's final xr slots
    int OA0 = -1, OA1 = -1, OA2 = -1, OA3 = -1, OA4 = -1, OA5 = -1;
    int OB0 = -1, OB1 = -1, OB2 = -1, OB3 = -1, OB4 = -1, OB5 = -1;

    // local half-argmax -> LDS (u32 fast path, exact u64 intra-wave fallback)
    auto amax_half = [&](const double* r, unsigned enc, int rsel) {
        unsigned k8[8];
#pragma unroll
        for (int s = 0; s < 8; ++s) {
            const unsigned key = hi_key(r[s]);
            k8[s] = (enc & (1u << s)) ? 0u : key;
        }
        unsigned lm = k8[0];
#pragma unroll
        for (int s = 1; s < 8; ++s) lm = k8[s] > lm ? k8[s] : lm;
        const unsigned g = wave_umax(lm);
        const unsigned long long tied = __ballot(lm == g);
        unsigned mm = 0;
#pragma unroll
        for (int s = 0; s < 8; ++s) mm |= (k8[s] == g) ? (1u << s) : 0u;
        const int L = (int)__ffsll((long long)tied) - 1;
        const unsigned mmL = (unsigned)__builtin_amdgcn_readlane((int)mm, L);
        int jw;
        if (__builtin_expect((__popcll(tied) == 1) && !(mmL & (mmL - 1)), 1)) {
            const int bi = __ffs(mmL) - 1;  // slot asc == j asc within lane
            jw = (wv << 9) | ((bi >> 2) << 8) | (L << 2) | (bi & 3);
        } else {  // exact intra-wave resolve among u32-tied candidates
            unsigned long long kb = 0;
#pragma unroll
            for (int s = 0; s < 8; ++s) {
                const int j = (wv << 9) | ((s >> 2) << 8) | (lane << 2) | (s & 3);
                const unsigned long long fk =
                    pack_key(r[s], 1023u ^ (unsigned)j, 1023ull);
                kb = (k8[s] == g && fk > kb) ? fk : kb;
            }
            const unsigned long long gk = wave_max_key(kb);
            jw = 1023 ^ (int)(gk & 1023ull);
        }
        if (lane == 0) {
            gu32[rsel][wv] = g;
            gjw[rsel][wv] = jw;
        }
    };

    // cross-wave merge (after B1); rare exact path has its own uniform barrier
    auto merge_row = [&](int rsel, const double* r, unsigned enc) -> int {
        const unsigned ga = gu32[rsel][0], gb = gu32[rsel][1];
        int bestj;
        if (__builtin_expect(ga != gb, 1)) {  // u32 strict order is f64-faithful
            bestj = (gb > ga) ? gjw[rsel][1] : gjw[rsel][0];
        } else {
            unsigned long long kb = 0;
#pragma unroll
            for (int s = 0; s < 8; ++s) {
                const int j = (wv << 9) | ((s >> 2) << 8) | (lane << 2) | (s & 3);
                const unsigned long long fk =
                    pack_key(r[s], 1023u ^ (unsigned)j, 1023ull);
                const bool cand = !(enc & (1u << s)) && hi_key(r[s]) == ga;
                kb = (cand && fk > kb) ? fk : kb;
            }
            const unsigned long long wm = wave_max_key(kb);
            if (lane == 0) kx[rsel][wv] = wm;
            __syncthreads();
            const unsigned long long A = kx[rsel][0], B = kx[rsel][1];
            bestj = 1023 ^ (int)((A > B ? A : B) & 1023ull);
        }
        return __builtin_amdgcn_readfirstlane(bestj);
    };

#pragma unroll 1
    for (int t = 0; t < K_ACTIVE; ++t) {
        // ---- both waves: half-argmax for BOTH rows (2 independent chains) ----
        amax_half(rA, encA, 0);
        amax_half(rB, encB, 1);
        __syncthreads();  // B1
        const int bestjA = merge_row(0, rA, encA);
        const int bestjB = merge_row(1, rB, encB);
        if ((bestjA >> 9) == wv && ((bestjA >> 2) & 63) == lane)
            encA |= 1u << ((((bestjA >> 8) & 1) << 2) | (bestjA & 3));
        if ((bestjB >> 9) == wv && ((bestjB >> 2) & 63) == lane)
            encB |= 1u << ((((bestjB >> 8) & 1) << 2) | (bestjB & 3));

        // ---- OWN row: v += W[bestj] then full kwta (both waves busy, no dup) ----
        {
            const int bj = wv ? bestjB : bestjA;
            const float* wr = w + ((size_t)bj << 9) + (lane << 2);
            const float4 f0 = *(const float4*)wr;
            const float4 f1 = *(const float4*)(wr + 256);
            vd[0] += (double)f0.x;  vd[1] += (double)f0.y;
            vd[2] += (double)f0.z;  vd[3] += (double)f0.w;
            vd[4] += (double)f1.x;  vd[5] += (double)f1.y;
            vd[6] += (double)f1.z;  vd[7] += (double)f1.w;

            unsigned kk[8];  // transient u32
#pragma unroll
            for (int p = 0; p < 8; ++p) kk[p] = hi_key(vd[p]);
#pragma unroll
            for (int s2 = 0; s2 < K_IN; ++s2) {
                unsigned lm = kk[0];
#pragma unroll
                for (int p = 1; p < 8; ++p) lm = kk[p] > lm ? kk[p] : lm;
                const unsigned g2 = wave_umax(lm);
                const unsigned long long tied2 = __ballot(lm == g2);
                unsigned mm2 = 0;
#pragma unroll
                for (int p = 0; p < 8; ++p) mm2 |= (kk[p] == g2) ? (1u << p) : 0u;
                const int L2 = (int)__ffsll((long long)tied2) - 1;
                const unsigned mmL2 =
                    (unsigned)__builtin_amdgcn_readlane((int)mm2, L2);
                int n;
                if (__builtin_expect((__popcll(tied2) == 1) && !(mmL2 & (mmL2 - 1)),
                                     1)) {
                    const int bp = __ffs(mmL2) - 1;
                    n = ((bp >> 2) << 8) | (L2 << 2) | (bp & 3);
#pragma unroll
                    for (int p = 0; p < 8; ++p) kk[p] = (kk[p] == g2) ? 0u : kk[p];
                } else {  // exact resolve among u32-tied candidates
                    unsigned long long kb = 0;
#pragma unroll
                    for (int p = 0; p < 8; ++p) {
                        const int i = ((p >> 2) << 8) | (lane << 2) | (p & 3);
                        const unsigned long long fk =
                            pack_key(vd[p], 511u ^ (unsigned)i, 511ull);
                        kb = (kk[p] == g2 && fk > kb) ? fk : kb;
                    }
                    const unsigned long long gk = wave_max_key(kb);
                    n = 511 ^ (int)(gk & 511ull);
                    const int ln = (n >> 2) & 63;
                    const int bp = (((n >> 8) & 1) << 2) | (n & 3);
#pragma unroll
                    for (int p = 0; p < 8; ++p)
                        kk[p] = (lane == ln && p == bp) ? 0u : kk[p];
                }
                if (lane == 0) msg[wv][1 + s2] = n;
            }
            if (t == K_ACTIVE - 1) {
                selmask = 0;  // cleared keys are 0 (0 unreachable for real values)
#pragma unroll
                for (int p = 0; p < 8; ++p) selmask |= (kk[p] == 0u) ? (1u << p) : 0u;
            }
        }
        __syncthreads();  // B2: winners of both rows -> both waves

        if (t < K_ACTIVE - 1) {
            const int NA0 = __builtin_amdgcn_readfirstlane(msg[0][1]);
            const int NA1 = __builtin_amdgcn_readfirstlane(msg[0][2]);
            const int NA2 = __builtin_amdgcn_readfirstlane(msg[0][3]);
            const int NA3 = __builtin_amdgcn_readfirstlane(msg[0][4]);
            const int NA4 = __builtin_amdgcn_readfirstlane(msg[0][5]);
            const int NA5 = __builtin_amdgcn_readfirstlane(msg[0][6]);
            const int NB0 = __builtin_amdgcn_readfirstlane(msg[1][1]);
            const int NB1 = __builtin_amdgcn_readfirstlane(msg[1][2]);
            const int NB2 = __builtin_amdgcn_readfirstlane(msg[1][3]);
            const int NB3 = __builtin_amdgcn_readfirstlane(msg[1][4]);
            const int NB4 = __builtin_amdgcn_readfirstlane(msg[1][5]);
            const int NB5 = __builtin_amdgcn_readfirstlane(msg[1][6]);

            // ---- row A set-diff axpy on own half ----
            if (t == 0) {
                if constexpr (MODE == 1) {
                    half_axpy(rA, wT, NA0, -1.0, lane, wv);
                    half_axpy(rA, wT, NA1, -1.0, lane, wv);
                    half_axpy(rA, wT, NA2, -1.0, lane, wv);
                    half_axpy(rA, wT, NA3, -1.0, lane, wv);
                    half_axpy(rA, wT, NA4, -1.0, lane, wv);
                    half_axpy(rA, wT, NA5, -1.0, lane, wv);
                } else {
                    half_axpy0(rA, w, NA0, -1.0, lane, wv);
                    half_axpy0(rA, w, NA1, -1.0, lane, wv);
                    half_axpy0(rA, w, NA2, -1.0, lane, wv);
                    half_axpy0(rA, w, NA3, -1.0, lane, wv);
                    half_axpy0(rA, w, NA4, -1.0, lane, wv);
                    half_axpy0(rA, w, NA5, -1.0, lane, wv);
                }
            } else {
#pragma unroll
                for (int a2 = 0; a2 < 6; ++a2) {
                    const int o = (a2 == 0) ? OA0 : (a2 == 1) ? OA1 : (a2 == 2) ? OA2
                                  : (a2 == 3) ? OA3 : (a2 == 4) ? OA4 : OA5;
                    const bool stay = (o == NA0) | (o == NA1) | (o == NA2) |
                                      (o == NA3) | (o == NA4) | (o == NA5);
                    if (!stay) {
                        if constexpr (MODE == 1) half_axpy(rA, wT, o, 1.0, lane, wv);
                        else half_axpy0(rA, w, o, 1.0, lane, wv);
                    }
                }
#pragma unroll
                for (int b2 = 0; b2 < 6; ++b2) {
                    const int n = (b2 == 0) ? NA0 : (b2 == 1) ? NA1 : (b2 == 2) ? NA2
                                  : (b2 == 3) ? NA3 : (b2 == 4) ? NA4 : NA5;
                    const bool was = (n == OA0) | (n == OA1) | (n == OA2) |
                                     (n == OA3) | (n == OA4) | (n == OA5);
                    if (!was) {
                        if constexpr (MODE == 1) half_axpy(rA, wT, n, -1.0, lane, wv);
                        else half_axpy0(rA, w, n, -1.0, lane, wv);
                    }
                }
            }
            // ---- row B set-diff axpy on own half ----
            if (t == 0) {
                if constexpr (MODE == 1) {
                    half_axpy(rB, wT, NB0, -1.0, lane, wv);
                    half_axpy(rB, wT, NB1, -1.0, lane, wv);
                    half_axpy(rB, wT, NB2, -1.0, lane, wv);
                    half_axpy(rB, wT, NB3, -1.0, lane, wv);
                    half_axpy(rB, wT, NB4, -1.0, lane, wv);
                    half_axpy(rB, wT, NB5, -1.0, lane, wv);
                } else {
                    half_axpy0(rB, w, NB0, -1.0, lane, wv);
                    half_axpy0(rB, w, NB1, -1.0, lane, wv);
                    half_axpy0(rB, w, NB2, -1.0, lane, wv);
                    half_axpy0(rB, w, NB3, -1.0, lane, wv);
                    half_axpy0(rB, w, NB4, -1.0, lane, wv);
                    half_axpy0(rB, w, NB5, -1.0, lane, wv);
                }
            } else {
#pragma unroll
                for (int a2 = 0; a2 < 6; ++a2) {
                    const int o = (a2 == 0) ? OB0 : (a2 == 1) ? OB1 : (a2 == 2) ? OB2
                                  : (a2 == 3) ? OB3 : (a2 == 4) ? OB4 : OB5;
                    const bool stay = (o == NB0) | (o == NB1) | (o == NB2) |
                                      (o == NB3) | (o == NB4) | (o == NB5);
                    if (!stay) {
                        if constexpr (MODE == 1) half_axpy(rB, wT, o, 1.0, lane, wv);
                        else half_axpy0(rB, w, o, 1.0, lane, wv);
                    }
                }
#pragma unroll
                for (int b2 = 0; b2 < 6; ++b2) {
                    const int n = (b2 == 0) ? NB0 : (b2 == 1) ? NB1 : (b2 == 2) ? NB2
                                  : (b2 == 3) ? NB3 : (b2 == 4) ? NB4 : NB5;
                    const bool was = (n == OB0) | (n == OB1) | (n == OB2) |
                                     (n == OB3) | (n == OB4) | (n == OB5);
                    if (!was) {
                        if constexpr (MODE == 1) half_axpy(rB, wT, n, -1.0, lane, wv);
                        else half_axpy0(rB, w, n, -1.0, lane, wv);
                    }
                }
            }
            OA0 = NA0; OA1 = NA1; OA2 = NA2; OA3 = NA3; OA4 = NA4; OA5 = NA5;
            OB0 = NB0; OB1 = NB1; OB2 = NB2; OB3 = NB3; OB4 = NB4; OB5 = NB5;
        }
    }

    // ---- outputs: encoded halves of both rows; xr of own row ----
    {
        float* oeA = out + (size_t)rowA * OUT_F + (wv << 9) + (lane << 2);
#pragma unroll
        for (int c = 0; c < 2; ++c) {
            float4 v;
            v.x = (encA & (1u << (4 * c + 0))) ? 1.0f : 0.0f;
            v.y = (encA & (1u << (4 * c + 1))) ? 1.0f : 0.0f;
            v.z = (encA & (1u << (4 * c + 2))) ? 1.0f : 0.0f;
            v.w = (encA & (1u << (4 * c + 3))) ? 1.0f : 0.0f;
            *(float4*)(oeA + (c << 8)) = v;
        }
        float* oeB = out + (size_t)rowB * OUT_F + (wv << 9) + (lane << 2);
#pragma unroll
        for (int c = 0; c < 2; ++c) {
            float4 v;
            v.x = (encB & (1u << (4 * c + 0))) ? 1.0f : 0.0f;
            v.y = (encB & (1u << (4 * c + 1))) ? 1.0f : 0.0f;
            v.z = (encB & (1u << (4 * c + 2))) ? 1.0f : 0.0f;
            v.w = (encB & (1u << (4 * c + 3))) ? 1.0f : 0.0f;
            *(float4*)(oeB + (c << 8)) = v;
        }
        float* ox = out + (size_t)rows * OUT_F + (size_t)myrow * IN_F + (lane << 2);
#pragma unroll
        for (int c = 0; c < 2; ++c) {
            float4 v;
            v.x = (selmask & (1u << (4 * c + 0))) ? 1.0f : 0.0f;
            v.y = (selmask & (1u << (4 * c + 1))) ? 1.0f : 0.0f;
            v.z = (selmask & (1u << (4 * c + 2))) ? 1.0f : 0.0f;
            v.w = (selmask & (1u << (4 * c + 3))) ? 1.0f : 0.0f;
            *(float4*)(ox + (c << 8)) = v;
        }
    }
}

extern "C" void kernel_launch(void* const* d_in, const int* in_sizes, int n_in,
                              void* d_out, int out_size, void* d_ws, size_t ws_size,
                              hipStream_t stream) {
    const float* x = (const float*)d_in[0];
    const float* w = (const float*)d_in[1];
    float* out = (float*)d_out;
    const int rows = in_sizes[0] / IN_F;  // 4096

    const size_t need_f = (size_t)(IN_F + 1) * OUT_F * sizeof(float);  // 2.1 MB
    const int blocks = (rows + 1) / 2;  // 2 rows per 2-wave block

    if (d_ws != nullptr && ws_size >= need_f) {
        float* wT = (float*)d_ws;
        transpose_w_kernel<<<dim3(IN_F / 32, OUT_F / 32), 256, 0, stream>>>(w, wT);
        zero_row_f_kernel<<<OUT_F / 256, 256, 0, stream>>>(wT);
        bmp_kernel<1><<<blocks, 128, 0, stream>>>(x, w, wT, out, rows);
    } else {
        bmp_kernel<0><<<blocks, 128, 0, stream>>>(x, w, nullptr, out, rows);
    }
}

// Round 14
// 152.338 us; speedup vs baseline: 1.2896x; 1.2896x over previous
//
#include <hip/hip_runtime.h>

#define IN_F 512
#define OUT_F 1024
#define K_ACTIVE 11  // ceil(0.01 * 1024) serial MP steps
#define K_IN 6       // ceil(0.01 * 512) kwta winners

// ---- w [1024][512] f32 -> wT [513][1024] f32 (row 512 = zeros, pad reads) ----
// wT is 2.1 MB: fits per-XCD L2 (4 MiB) together with w (2 MB). R6 measured fp64
// wT (4.2 MB) thrashing L2 -> 156 MB HBM fetch, +34 us. Keep f32.
__global__ __launch_bounds__(256) void transpose_w_kernel(const float* __restrict__ w,
                                                          float* __restrict__ wT) {
    __shared__ float tile[32][33];
    const int tx = threadIdx.x & 31;
    const int ty = threadIdx.x >> 5;  // 0..7
    const int i0 = blockIdx.x * 32;
    const int j0 = blockIdx.y * 32;
#pragma unroll
    for (int k = 0; k < 4; ++k)
        tile[ty + 8 * k][tx] = w[(size_t)(j0 + ty + 8 * k) * IN_F + (i0 + tx)];
    __syncthreads();
#pragma unroll
    for (int k = 0; k < 4; ++k)
        wT[(size_t)(i0 + ty + 8 * k) * OUT_F + (j0 + tx)] = tile[tx][ty + 8 * k];
}
__global__ void zero_row_f_kernel(float* __restrict__ wT) {
    wT[(size_t)IN_F * OUT_F + blockIdx.x * 256 + threadIdx.x] = 0.0f;
}

// ---- order-preserving fp64 -> u64 key, low bits carry reversed index ----
__device__ __forceinline__ unsigned long long pack_key(double v, unsigned rev,
                                                       unsigned long long mask) {
    unsigned long long b = (unsigned long long)__double_as_longlong(v);
    unsigned long long m =
        (unsigned long long)((long long)b >> 63) | 0x8000000000000000ull;
    unsigned long long u = b ^ m;  // monotonic total order
    return (u & ~mask) | (unsigned long long)rev;
}

// ---- monotonic u32 key from the f64 HIGH word ----
__device__ __forceinline__ unsigned hi_key(double v) {
    const int hi = __double2hiint(v);
    return (unsigned)hi ^ ((unsigned)(hi >> 31) | 0x80000000u);
}

// ---- wave max of u32 via DPP chain (bound_ctrl=true: invalid lanes -> 0) ----
template <int C>
__device__ __forceinline__ unsigned maxdpp(unsigned v) {
    unsigned t = (unsigned)__builtin_amdgcn_update_dpp(0, (int)v, C, 0xF, 0xF, true);
    return t > v ? t : v;
}
__device__ __forceinline__ unsigned wave_umax(unsigned v) {
    v = maxdpp<0x111>(v);  // row_shr:1
    v = maxdpp<0x112>(v);  // row_shr:2
    v = maxdpp<0x114>(v);  // row_shr:4
    v = maxdpp<0x118>(v);  // row_shr:8
    v = maxdpp<0x142>(v);  // row_bcast:15
    v = maxdpp<0x143>(v);  // row_bcast:31 -> lane 63 holds wave max
    return (unsigned)__builtin_amdgcn_readlane((int)v, 63);
}

// ---- exact wave max of u64 key (rare path): high32 chain + tie resolve ----
__device__ __forceinline__ unsigned long long wave_max_key(unsigned long long k) {
    const unsigned h = (unsigned)(k >> 32), l = (unsigned)k;
    const unsigned gh = wave_umax(h);
    const unsigned long long tied = __ballot(h == gh);
    unsigned gl;
    if (__popcll(tied) == 1) {
        gl = (unsigned)__builtin_amdgcn_readlane((int)l,
                                                 (int)__ffsll((long long)tied) - 1);
    } else {
        gl = wave_umax((h == gh) ? l : 0u);
    }
    return ((unsigned long long)gh << 32) | gl;
}

// MODE0 fallbacks (no workspace): strided gathers from row-major w
__device__ __forceinline__ void half_add0(double* rh, const float* __restrict__ w,
                                          int i, int lane, int wv) {
#pragma unroll
    for (int s = 0; s < 8; ++s) {
        const int j = (wv << 9) | ((s >> 2) << 8) | (lane << 2) | (s & 3);
        rh[s] += (double)w[(size_t)j * IN_F + i];
    }
}
__device__ __forceinline__ void half_axpy0(double* rh, const float* __restrict__ w,
                                           int i, double sgn, int lane, int wv) {
#pragma unroll
    for (int s = 0; s < 8; ++s) {
        const int j = (wv << 9) | ((s >> 2) << 8) | (lane << 2) | (s & 3);
        rh[s] += sgn * (double)w[(size_t)j * IN_F + i];
    }
}

// R10 structure (best: 154us) + latency de-serialization:
//  * projection loop software-pipelined (prefetch next pair before adds) -> one
//    exposed L2 latency instead of ~26
//  * set-diff axpy driven by a tiny uniform LDS list built ONCE by wave0-lane0
//    (removes duplicated stay/was scalar logic + msg/readfirstlanes) and run as
//    a 2-deep pipelined loop -> one exposed L2 latency per step, batched loads
template <int MODE>
__global__ __launch_bounds__(128) void bmp_kernel(const float* __restrict__ x,
                                                  const float* __restrict__ w,
                                                  const float* __restrict__ wT,
                                                  float* __restrict__ out, int rows) {
    __shared__ unsigned short act[IN_F + 8];
    __shared__ unsigned gu32[2][2];       // parity: argmax merge (u32 key)
    __shared__ int gjw[2][2];             // parity: argmax merge (index)
    __shared__ unsigned long long kx[2];  // rare exact cross-wave u64 merge
    __shared__ int axlist[16];            // set-diff list: idx (add) or ~idx (sub)
    __shared__ int axn;
    const int lane = threadIdx.x & 63;
    const int wv = threadIdx.x >> 6;
    const int row = blockIdx.x;
    if (row >= rows) return;

    // ---- compacted active list of x row (both waves same ballots; wv0 writes) ----
    const float* xrow = x + (size_t)row * IN_F;
    int cnt = 0;
#pragma unroll
    for (int c = 0; c < IN_F / 64; ++c) {
        bool pbit = xrow[c * 64 + lane] != 0.0f;
        unsigned long long m = __ballot(pbit);
        int pre = __popcll(m & ((1ull << lane) - 1ull));
        if (wv == 0 && pbit) act[cnt + pre] = (unsigned short)(c * 64 + lane);
        cnt += __popcll(m);
    }
    if (wv == 0 && lane < 2) act[cnt + lane] = (unsigned short)IN_F;  // zero-row pad
    __syncthreads();

    // ---- r = 2 * x @ wT on own OUT-half, software-pipelined (1-pair lookahead) ----
    double r[8];
#pragma unroll
    for (int s = 0; s < 8; ++s) r[s] = 0.0;
    if constexpr (MODE == 1) {
        const int base = (wv << 9) + (lane << 2);
        const float* pa = wT + ((size_t)act[0] << 10) + base;
        const float* pb = wT + ((size_t)act[1] << 10) + base;
        float4 c0 = *(const float4*)pa, c1 = *(const float4*)(pa + 256);
        float4 c2 = *(const float4*)pb, c3 = *(const float4*)(pb + 256);
#pragma unroll 1
        for (int k = 0; k < cnt; k += 2) {
            float4 n0 = c0, n1 = c1, n2 = c2, n3 = c3;
            if (k + 2 < cnt) {  // act zero-padded by 2 -> act[k+3] always valid
                const float* qa = wT + ((size_t)act[k + 2] << 10) + base;
                const float* qb = wT + ((size_t)act[k + 3] << 10) + base;
                n0 = *(const float4*)qa;  n1 = *(const float4*)(qa + 256);
                n2 = *(const float4*)qb;  n3 = *(const float4*)(qb + 256);
            }
            r[0] += (double)c0.x + (double)c2.x;  r[1] += (double)c0.y + (double)c2.y;
            r[2] += (double)c0.z + (double)c2.z;  r[3] += (double)c0.w + (double)c2.w;
            r[4] += (double)c1.x + (double)c3.x;  r[5] += (double)c1.y + (double)c3.y;
            r[6] += (double)c1.z + (double)c3.z;  r[7] += (double)c1.w + (double)c3.w;
            c0 = n0; c1 = n1; c2 = n2; c3 = n3;
        }
    } else {
#pragma unroll 1
        for (int k = 0; k < cnt; ++k) half_add0(r, w, act[k], lane, wv);
    }
#pragma unroll
    for (int s = 0; s < 8; ++s) r[s] *= 2.0;

    double vd[8];  // full v = encoded @ W, live only on wave 0 (static indices)
#pragma unroll
    for (int p = 0; p < 8; ++p) vd[p] = 0.0;

    unsigned enc = 0;      // per-lane 8-bit slot mask over own OUT slots
    unsigned selmask = 0;  // wave0: final-step xr slots
    int O0 = -1, O1 = -1, O2 = -1, O3 = -1, O4 = -1, O5 = -1;  // wave0 only

#pragma unroll 1
    for (int t = 0; t < K_ACTIVE; ++t) {
        // ---- argmax of residual over non-encoded j (lambd => exclusion) ----
        unsigned k8[8];  // transient u32 keys, alive through the cross merge
#pragma unroll
        for (int s = 0; s < 8; ++s) {
            const unsigned key = hi_key(r[s]);
            k8[s] = (enc & (1u << s)) ? 0u : key;
        }
        {
            unsigned lm = k8[0];
#pragma unroll
            for (int s = 1; s < 8; ++s) lm = k8[s] > lm ? k8[s] : lm;
            const unsigned g = wave_umax(lm);
            const unsigned long long tied = __ballot(lm == g);
            unsigned mm = 0;
#pragma unroll
            for (int s = 0; s < 8; ++s) mm |= (k8[s] == g) ? (1u << s) : 0u;
            const int L = (int)__ffsll((long long)tied) - 1;
            const unsigned mmL = (unsigned)__builtin_amdgcn_readlane((int)mm, L);
            int jw;
            if (__builtin_expect((__popcll(tied) == 1) && !(mmL & (mmL - 1)), 1)) {
                const int bi = __ffs(mmL) - 1;  // slot asc == j asc within lane
                jw = (wv << 9) | ((bi >> 2) << 8) | (L << 2) | (bi & 3);
            } else {  // exact intra-wave resolve among u32-tied candidates
                unsigned long long kb = 0;
#pragma unroll
                for (int s = 0; s < 8; ++s) {
                    const int j = (wv << 9) | ((s >> 2) << 8) | (lane << 2) | (s & 3);
                    const unsigned long long fk =
                        pack_key(r[s], 1023u ^ (unsigned)j, 1023ull);
                    kb = (k8[s] == g && fk > kb) ? fk : kb;
                }
                const unsigned long long gk = wave_max_key(kb);
                jw = 1023 ^ (int)(gk & 1023ull);
            }
            if (lane == 0) {
                gu32[t & 1][wv] = g;
                gjw[t & 1][wv] = jw;
            }
        }
        __syncthreads();  // B1: merge the two half-maxima
        const unsigned ga = gu32[t & 1][0], gb = gu32[t & 1][1];
        int bestj;
        if (__builtin_expect(ga != gb, 1)) {  // u32 strict order is f64-faithful
            bestj = (gb > ga) ? gjw[t & 1][1] : gjw[t & 1][0];
        } else {  // rare: exact cross-wave u64 merge (uniform branch, own barrier)
            unsigned long long kb = 0;
#pragma unroll
            for (int s = 0; s < 8; ++s) {
                const int j = (wv << 9) | ((s >> 2) << 8) | (lane << 2) | (s & 3);
                const unsigned long long fk =
                    pack_key(r[s], 1023u ^ (unsigned)j, 1023ull);
                kb = (k8[s] == ga && fk > kb) ? fk : kb;
            }
            const unsigned long long wm = wave_max_key(kb);
            if (lane == 0) kx[wv] = wm;
            __syncthreads();
            const unsigned long long A = kx[0], B = kx[1];
            bestj = 1023 ^ (int)((A > B ? A : B) & 1023ull);
        }
        bestj = __builtin_amdgcn_readfirstlane(bestj);
        if ((bestj >> 9) == wv && ((bestj >> 2) & 63) == lane)
            enc |= 1u << ((((bestj >> 8) & 1) << 2) | (bestj & 3));

        if (wv == 0) {
            // ---- v += W[bestj][:] (two 1KB-contiguous float4 loads) ----
            const float* wr = w + ((size_t)bestj << 9) + (lane << 2);
            const float4 f0 = *(const float4*)wr;
            const float4 f1 = *(const float4*)(wr + 256);
            vd[0] += (double)f0.x;  vd[1] += (double)f0.y;
            vd[2] += (double)f0.z;  vd[3] += (double)f0.w;
            vd[4] += (double)f1.x;  vd[5] += (double)f1.y;
            vd[6] += (double)f1.z;  vd[7] += (double)f1.w;

            // ---- kwta: top-6 of v, u32 keys packed once, 6 wave-local rounds ----
            int N[6];
            unsigned kk[8];  // transient
#pragma unroll
            for (int p = 0; p < 8; ++p) kk[p] = hi_key(vd[p]);
#pragma unroll
            for (int s2 = 0; s2 < K_IN; ++s2) {
                unsigned lm = kk[0];
#pragma unroll
                for (int p = 1; p < 8; ++p) lm = kk[p] > lm ? kk[p] : lm;
                const unsigned g2 = wave_umax(lm);
                const unsigned long long tied2 = __ballot(lm == g2);
                unsigned mm2 = 0;
#pragma unroll
                for (int p = 0; p < 8; ++p) mm2 |= (kk[p] == g2) ? (1u << p) : 0u;
                const int L2 = (int)__ffsll((long long)tied2) - 1;
                const unsigned mmL2 =
                    (unsigned)__builtin_amdgcn_readlane((int)mm2, L2);
                int n;
                if (__builtin_expect((__popcll(tied2) == 1) && !(mmL2 & (mmL2 - 1)),
                                     1)) {
                    const int bp = __ffs(mmL2) - 1;
                    n = ((bp >> 2) << 8) | (L2 << 2) | (bp & 3);
                    // unique candidate: clear by value (exactly one slot matches)
#pragma unroll
                    for (int p = 0; p < 8; ++p) kk[p] = (kk[p] == g2) ? 0u : kk[p];
                } else {  // exact resolve among u32-tied candidates
                    unsigned long long kb = 0;
#pragma unroll
                    for (int p = 0; p < 8; ++p) {
                        const int i = ((p >> 2) << 8) | (lane << 2) | (p & 3);
                        const unsigned long long fk =
                            pack_key(vd[p], 511u ^ (unsigned)i, 511ull);
                        kb = (kk[p] == g2 && fk > kb) ? fk : kb;
                    }
                    const unsigned long long gk = wave_max_key(kb);
                    n = 511 ^ (int)(gk & 511ull);
                    const int ln = (n >> 2) & 63;
                    const int bp = (((n >> 8) & 1) << 2) | (n & 3);
#pragma unroll
                    for (int p = 0; p < 8; ++p)
                        kk[p] = (lane == ln && p == bp) ? 0u : kk[p];
                }
                N[s2] = __builtin_amdgcn_readfirstlane(n);
            }
            if (t == K_ACTIVE - 1) {
                selmask = 0;  // cleared keys are 0 (0 unreachable for real values)
#pragma unroll
                for (int p = 0; p < 8; ++p) selmask |= (kk[p] == 0u) ? (1u << p) : 0u;
            }

            // ---- build set-diff list ONCE (uniform; lane0 serial, ~30 ops) ----
            if (lane == 0) {
                int n2 = 0;
                if (t == 0) {
#pragma unroll
                    for (int b = 0; b < 6; ++b) axlist[n2++] = ~N[b];  // subtract
                } else if (t < K_ACTIVE - 1) {
#pragma unroll
                    for (int a2 = 0; a2 < 6; ++a2) {
                        const int o = (a2 == 0) ? O0 : (a2 == 1) ? O1 : (a2 == 2) ? O2
                                      : (a2 == 3) ? O3 : (a2 == 4) ? O4 : O5;
                        const bool stay = (o == N[0]) | (o == N[1]) | (o == N[2]) |
                                          (o == N[3]) | (o == N[4]) | (o == N[5]);
                        if (!stay) axlist[n2++] = o;  // add back
                    }
#pragma unroll
                    for (int b = 0; b < 6; ++b) {
                        const int nn = N[b];
                        const bool was = (nn == O0) | (nn == O1) | (nn == O2) |
                                         (nn == O3) | (nn == O4) | (nn == O5);
                        if (!was) axlist[n2++] = ~nn;  // subtract
                    }
                }
                axn = n2;
            }
            O0 = N[0]; O1 = N[1]; O2 = N[2]; O3 = N[3]; O4 = N[4]; O5 = N[5];
        }
        __syncthreads();  // B2: list -> both waves

        // ---- pipelined set-diff axpy on own half (one exposed L2 latency) ----
        const int nax = axn;  // uniform
        if (nax > 0) {
            if constexpr (MODE == 1) {
                const int base = (wv << 9) + (lane << 2);
                int e0 = axlist[0];
                {
                    const int i0 = (e0 < 0) ? ~e0 : e0;
                    const float* p = wT + ((size_t)i0 << 10) + base;
                    float4 A0 = *(const float4*)p;
                    float4 A1 = *(const float4*)(p + 256);
#pragma unroll 1
                    for (int k = 0; k < nax; ++k) {
                        float4 B0 = A0, B1 = A1;
                        int e1 = 0;
                        if (k + 1 < nax) {
                            e1 = axlist[k + 1];
                            const int i1 = (e1 < 0) ? ~e1 : e1;
                            const float* q = wT + ((size_t)i1 << 10) + base;
                            B0 = *(const float4*)q;
                            B1 = *(const float4*)(q + 256);
                        }
                        const double sg = (e0 < 0) ? -1.0 : 1.0;
                        r[0] += sg * (double)A0.x;  r[1] += sg * (double)A0.y;
                        r[2] += sg * (double)A0.z;  r[3] += sg * (double)A0.w;
                        r[4] += sg * (double)A1.x;  r[5] += sg * (double)A1.y;
                        r[6] += sg * (double)A1.z;  r[7] += sg * (double)A1.w;
                        A0 = B0; A1 = B1; e0 = e1;
                    }
                }
            } else {
#pragma unroll 1
                for (int k = 0; k < nax; ++k) {
                    const int e = axlist[k];
                    const int i = (e < 0) ? ~e : e;
                    half_axpy0(r, w, i, (e < 0) ? -1.0 : 1.0, lane, wv);
                }
            }
        }
    }

    // ---- outputs: encoded halves (each wave), xr (wave0), coalesced float4 ----
    float* oe = out + (size_t)row * OUT_F + (wv << 9) + (lane << 2);
#pragma unroll
    for (int c = 0; c < 2; ++c) {
        float4 v;
        v.x = (enc & (1u << (4 * c + 0))) ? 1.0f : 0.0f;
        v.y = (enc & (1u << (4 * c + 1))) ? 1.0f : 0.0f;
        v.z = (enc & (1u << (4 * c + 2))) ? 1.0f : 0.0f;
        v.w = (enc & (1u << (4 * c + 3))) ? 1.0f : 0.0f;
        *(float4*)(oe + (c << 8)) = v;
    }
    if (wv == 0) {
        float* ox = out + (size_t)rows * OUT_F + (size_t)row * IN_F + (lane << 2);
#pragma unroll
        for (int c = 0; c < 2; ++c) {
            float4 v;
            v.x = (selmask & (1u << (4 * c + 0))) ? 1.0f : 0.0f;
            v.y = (selmask & (1u << (4 * c + 1))) ? 1.0f : 0.0f;
            v.z = (selmask & (1u << (4 * c + 2))) ? 1.0f : 0.0f;
            v.w = (selmask & (1u << (4 * c + 3))) ? 1.0f : 0.0f;
            *(float4*)(ox + (c << 8)) = v;
        }
    }
}

extern "C" void kernel_launch(void* const* d_in, const int* in_sizes, int n_in,
                              void* d_out, int out_size, void* d_ws, size_t ws_size,
                              hipStream_t stream) {
    const float* x = (const float*)d_in[0];
    const float* w = (const float*)d_in[1];
    float* out = (float*)d_out;
    const int rows = in_sizes[0] / IN_F;  // 4096

    const size_t need_f = (size_t)(IN_F + 1) * OUT_F * sizeof(float);  // 2.1 MB

    if (d_ws != nullptr && ws_size >= need_f) {
        float* wT = (float*)d_ws;
        transpose_w_kernel<<<dim3(IN_F / 32, OUT_F / 32), 256, 0, stream>>>(w, wT);
        zero_row_f_kernel<<<OUT_F / 256, 256, 0, stream>>>(wT);
        bmp_kernel<1><<<rows, 128, 0, stream>>>(x, w, wT, out, rows);
    } else {
        bmp_kernel<0><<<rows, 128, 0, stream>>>(x, w, nullptr, out, rows);
    }
}